// Round 1
// baseline (98.421 us; speedup 1.0000x reference)
//
#include <hip/hip_runtime.h>

// DPLoss: masked per-row MSE of (pred - log(alignment)) over first L elements,
// divided by L, then mean over rows.
//
// Kernel 1: 1 block (256 thr) per row -> row_mse[row] in d_ws (float[B]).
//           Reads only ceil(L/4) float4 groups per row (skips masked tail).
// Kernel 2: 1 block reduces B row values -> d_out[0] = mean.

__global__ __launch_bounds__(256) void dploss_row_kernel(
    const float* __restrict__ pred,
    const float* __restrict__ align,
    const int* __restrict__ lens,
    float* __restrict__ row_out,
    int T)
{
    const int row = blockIdx.x;
    const int L = lens[row];
    const float4* __restrict__ p4 = (const float4*)(pred + (size_t)row * T);
    const float4* __restrict__ a4 = (const float4*)(align + (size_t)row * T);
    const int ngroups = (L + 3) >> 2;   // float4 groups that contain any valid element

    float acc = 0.0f;
    for (int g = threadIdx.x; g < ngroups; g += 256) {
        float4 p = p4[g];
        float4 a = a4[g];
        const int base = g << 2;
        if (base + 4 <= L) {            // fully valid group (common case)
            float d0 = p.x - __logf(a.x);
            float d1 = p.y - __logf(a.y);
            float d2 = p.z - __logf(a.z);
            float d3 = p.w - __logf(a.w);
            acc += d0 * d0 + d1 * d1 + d2 * d2 + d3 * d3;
        } else {                        // tail group: per-element mask
            if (base + 0 < L) { float d = p.x - __logf(a.x); acc += d * d; }
            if (base + 1 < L) { float d = p.y - __logf(a.y); acc += d * d; }
            if (base + 2 < L) { float d = p.z - __logf(a.z); acc += d * d; }
        }
    }

    // wave-64 shuffle reduction
    #pragma unroll
    for (int off = 32; off > 0; off >>= 1)
        acc += __shfl_down(acc, off, 64);

    __shared__ float wsum[4];
    const int lane = threadIdx.x & 63;
    const int wave = threadIdx.x >> 6;
    if (lane == 0) wsum[wave] = acc;
    __syncthreads();
    if (threadIdx.x == 0) {
        float total = wsum[0] + wsum[1] + wsum[2] + wsum[3];
        row_out[row] = total / (float)L;
    }
}

__global__ __launch_bounds__(256) void dploss_mean_kernel(
    const float* __restrict__ row_out,
    float* __restrict__ out,
    int B)
{
    float acc = 0.0f;
    for (int i = threadIdx.x; i < B; i += 256)
        acc += row_out[i];

    #pragma unroll
    for (int off = 32; off > 0; off >>= 1)
        acc += __shfl_down(acc, off, 64);

    __shared__ float wsum[4];
    const int lane = threadIdx.x & 63;
    const int wave = threadIdx.x >> 6;
    if (lane == 0) wsum[wave] = acc;
    __syncthreads();
    if (threadIdx.x == 0)
        out[0] = (wsum[0] + wsum[1] + wsum[2] + wsum[3]) / (float)B;
}

extern "C" void kernel_launch(void* const* d_in, const int* in_sizes, int n_in,
                              void* d_out, int out_size, void* d_ws, size_t ws_size,
                              hipStream_t stream)
{
    const float* pred  = (const float*)d_in[0];
    const float* align = (const float*)d_in[1];
    const int*   lens  = (const int*)d_in[2];

    const int B = in_sizes[2];
    const int T = in_sizes[0] / B;

    float* row_out = (float*)d_ws;     // B floats of scratch
    float* out     = (float*)d_out;

    dploss_row_kernel<<<B, 256, 0, stream>>>(pred, align, lens, row_out, T);
    dploss_mean_kernel<<<1, 256, 0, stream>>>(row_out, out, B);
}

// Round 2
// 96.637 us; speedup vs baseline: 1.0185x; 1.0185x over previous
//
#include <hip/hip_runtime.h>

// DPLoss fused single-kernel version.
// One wave (64 lanes) per row: float4 loads of pred/align up to ceil(L/4)
// groups (masked tail handled in-wave), shuffle reduce, per-block LDS reduce
// over 8 waves, one atomicAdd(d_out) per block. d_out zeroed via memset node.

__global__ __launch_bounds__(512) void dploss_fused_kernel(
    const float* __restrict__ pred,
    const float* __restrict__ align,
    const int* __restrict__ lens,
    float* __restrict__ out,
    int B, int T)
{
    const int gtid = blockIdx.x * blockDim.x + threadIdx.x;
    const int wave = gtid >> 6;           // global wave id == row
    const int lane = threadIdx.x & 63;
    const int wave_in_block = threadIdx.x >> 6;

    float row_mse = 0.0f;

    if (wave < B) {
        const int row = wave;
        const int L = lens[row];          // wave-uniform -> scalar load
        const float4* __restrict__ p4 = (const float4*)(pred + (size_t)row * T);
        const float4* __restrict__ a4 = (const float4*)(align + (size_t)row * T);
        const int ngroups = (L + 3) >> 2;

        float acc = 0.0f;
        for (int g = lane; g < ngroups; g += 64) {
            float4 p = p4[g];
            float4 a = a4[g];
            const int base = g << 2;
            if (base + 4 <= L) {          // fully valid group (common case)
                float d0 = p.x - __logf(a.x);
                float d1 = p.y - __logf(a.y);
                float d2 = p.z - __logf(a.z);
                float d3 = p.w - __logf(a.w);
                acc += d0 * d0 + d1 * d1 + d2 * d2 + d3 * d3;
            } else {                      // tail group
                if (base + 0 < L) { float d = p.x - __logf(a.x); acc += d * d; }
                if (base + 1 < L) { float d = p.y - __logf(a.y); acc += d * d; }
                if (base + 2 < L) { float d = p.z - __logf(a.z); acc += d * d; }
            }
        }

        // wave-64 shuffle reduction
        #pragma unroll
        for (int off = 32; off > 0; off >>= 1)
            acc += __shfl_down(acc, off, 64);

        row_mse = acc / (float)L;         // only lane 0's value is used
    }

    __shared__ float wsum[8];
    if (lane == 0) wsum[wave_in_block] = row_mse;
    __syncthreads();

    if (threadIdx.x == 0) {
        float total = 0.0f;
        #pragma unroll
        for (int w = 0; w < 8; ++w) total += wsum[w];
        atomicAdd(out, total / (float)B);
    }
}

extern "C" void kernel_launch(void* const* d_in, const int* in_sizes, int n_in,
                              void* d_out, int out_size, void* d_ws, size_t ws_size,
                              hipStream_t stream)
{
    const float* pred  = (const float*)d_in[0];
    const float* align = (const float*)d_in[1];
    const int*   lens  = (const int*)d_in[2];

    const int B = in_sizes[2];
    const int T = in_sizes[0] / B;

    float* out = (float*)d_out;

    // zero the scalar accumulator (captured as a memset node)
    hipMemsetAsync(out, 0, sizeof(float), stream);

    const int threads = 512;                       // 8 waves per block
    const int waves_per_block = threads / 64;
    const int grid = (B + waves_per_block - 1) / waves_per_block;

    dploss_fused_kernel<<<grid, threads, 0, stream>>>(pred, align, lens, out, B, T);
}

// Round 3
// 94.790 us; speedup vs baseline: 1.0383x; 1.0195x over previous
//
#include <hip/hip_runtime.h>

// DPLoss fused single-kernel, v3.
// - 1024-thread blocks (16 waves) -> exactly 1 block/CU at B=4096, 256 atomics total.
// - Branch-free main loop over fully-valid float4 groups (compiler can unroll/
//   pipeline); <=3-element tail handled by the first lanes with scalar loads.
// - Per-wave shuffle reduce -> per-block LDS reduce -> one atomicAdd per block.
// - d_out zeroed via a captured hipMemsetAsync node.

__global__ __launch_bounds__(1024) void dploss_fused_kernel(
    const float* __restrict__ pred,
    const float* __restrict__ align,
    const int* __restrict__ lens,
    float* __restrict__ out,
    int B, int T)
{
    const int gtid = blockIdx.x * blockDim.x + threadIdx.x;
    const int wave = gtid >> 6;           // global wave id == row
    const int lane = threadIdx.x & 63;
    const int wave_in_block = threadIdx.x >> 6;

    float row_mse = 0.0f;

    if (wave < B) {
        const int row = wave;
        const int L = lens[row];          // wave-uniform -> scalar load
        const float* __restrict__ prow = pred  + (size_t)row * T;
        const float* __restrict__ arow = align + (size_t)row * T;
        const float4* __restrict__ p4 = (const float4*)prow;
        const float4* __restrict__ a4 = (const float4*)arow;
        const int nfull = L >> 2;         // fully-valid float4 groups

        float acc = 0.0f;
        #pragma unroll 2
        for (int g = lane; g < nfull; g += 64) {
            float4 p = p4[g];
            float4 a = a4[g];
            float d0 = p.x - __logf(a.x);
            float d1 = p.y - __logf(a.y);
            float d2 = p.z - __logf(a.z);
            float d3 = p.w - __logf(a.w);
            acc += d0 * d0 + d1 * d1 + d2 * d2 + d3 * d3;
        }

        // tail: L & 3 leftover elements, one per lane
        const int rem = L & 3;
        if (lane < rem) {
            const int idx = (nfull << 2) + lane;
            float d = prow[idx] - __logf(arow[idx]);
            acc += d * d;
        }

        // wave-64 shuffle reduction
        #pragma unroll
        for (int off = 32; off > 0; off >>= 1)
            acc += __shfl_down(acc, off, 64);

        row_mse = acc / (float)L;         // only lane 0's value matters
    }

    __shared__ float wsum[16];
    if (lane == 0) wsum[wave_in_block] = row_mse;
    __syncthreads();

    if (threadIdx.x == 0) {
        float total = 0.0f;
        #pragma unroll
        for (int w = 0; w < 16; ++w) total += wsum[w];
        atomicAdd(out, total / (float)B);
    }
}

extern "C" void kernel_launch(void* const* d_in, const int* in_sizes, int n_in,
                              void* d_out, int out_size, void* d_ws, size_t ws_size,
                              hipStream_t stream)
{
    const float* pred  = (const float*)d_in[0];
    const float* align = (const float*)d_in[1];
    const int*   lens  = (const int*)d_in[2];

    const int B = in_sizes[2];
    const int T = in_sizes[0] / B;

    float* out = (float*)d_out;

    // zero the scalar accumulator (captured as a memset node)
    hipMemsetAsync(out, 0, sizeof(float), stream);

    const int threads = 1024;                      // 16 waves per block
    const int waves_per_block = threads / 64;
    const int grid = (B + waves_per_block - 1) / waves_per_block;

    dploss_fused_kernel<<<grid, threads, 0, stream>>>(pred, align, lens, out, B, T);
}